// Round 9
// baseline (265.549 us; speedup 1.0000x reference)
//
#include <hip/hip_runtime.h>
#include <stdint.h>

typedef __bf16 bf16;
typedef __bf16 bf16x4 __attribute__((ext_vector_type(4)));
typedef __bf16 bf16x8 __attribute__((ext_vector_type(8)));
typedef float f32x4 __attribute__((ext_vector_type(4)));
typedef short short4v __attribute__((ext_vector_type(4)));

#define NB 4
#define NS 2048
#define ND 1024
#define NH 16
#define NHD 64
#define QSCALE 0.1803368801111204f   // 0.125 * log2(e): scores in log2 domain
#define FMAX   8.0f                  // fixed softmax shift (log2 domain)
#define CPITCH 136                   // epilogue LDS pitch: 272B rows, 16B aligned

typedef const __attribute__((address_space(1))) unsigned GU;
typedef __attribute__((address_space(3))) unsigned LU;

#define WAIT_VM(n) asm volatile("s_waitcnt vmcnt(" #n ")" ::: "memory")
#define BAR() do { asm volatile("" ::: "memory"); __builtin_amdgcn_s_barrier(); \
                   asm volatile("" ::: "memory"); } while (0)

__device__ __forceinline__ bf16x8 load8f(const float* p) {
    float4 a = *(const float4*)p;
    float4 b = *(const float4*)(p + 4);
    bf16x8 r;
    r[0] = (bf16)a.x; r[1] = (bf16)a.y; r[2] = (bf16)a.z; r[3] = (bf16)a.w;
    r[4] = (bf16)b.x; r[5] = (bf16)b.y; r[6] = (bf16)b.z; r[7] = (bf16)b.w;
    return r;
}
__device__ __forceinline__ void store8(bf16* p, bf16x8 v) { *(bf16x8*)p = v; }
__device__ __forceinline__ void store8(float* p, bf16x8 v) {
    float4 a; a.x = (float)v[0]; a.y = (float)v[1]; a.z = (float)v[2]; a.w = (float)v[3];
    float4 b; b.x = (float)v[4]; b.y = (float)v[5]; b.z = (float)v[6]; b.w = (float)v[7];
    *(float4*)p = a; *(float4*)(p + 4) = b;
}

// 16x16x16 bf16 MFMA (K=16): A/B frags are 4 bf16/lane, k = quad*4+j.
__device__ __forceinline__ f32x4 mfma16(bf16x4 a, bf16x4 b, f32x4 c) {
#ifdef __HIP_DEVICE_COMPILE__
#if __has_builtin(__builtin_amdgcn_mfma_f32_16x16x16bf16_1k)
    return __builtin_amdgcn_mfma_f32_16x16x16bf16_1k(
        __builtin_bit_cast(short4v, a), __builtin_bit_cast(short4v, b), c, 0, 0, 0);
#else
    f32x4 d;
    asm("v_mfma_f32_16x16x16_bf16 %0, %1, %2, %3"
        : "=v"(d) : "v"(a), "v"(b), "v"(c));
    return d;
#endif
#else
    return c;  // host stub, never executed
#endif
}

// attn LDS swizzle: XOR col by quad-of-row*16; preserves >=4-elem contiguity.
__device__ __forceinline__ int sw(int row, int col) {
    return row * 72 + (col ^ (((row >> 2) & 3) * 16));
}

// One-shot fp32 -> bf16 conversion of x, Wqkv, Wproj (biases stay fp32).
__global__ __launch_bounds__(256)
void convert_kernel(const float* __restrict__ s0, bf16* __restrict__ d0, int n0,
                    const float* __restrict__ s1, bf16* __restrict__ d1, int n1,
                    const float* __restrict__ s2, bf16* __restrict__ d2, int n2)
{
    int idx = (blockIdx.x * 256 + threadIdx.x) * 8;
    const float* s; bf16* d;
    if (idx < n0)              { s = s0 + idx;  d = d0 + idx; }
    else if ((idx -= n0) < n1) { s = s1 + idx;  d = d1 + idx; }
    else if ((idx -= n1) < n2) { s = s2 + idx;  d = d2 + idx; }
    else return;
    *(bf16x8*)d = load8f(s);
}

// ---------------- 128x128-tile GEMM, BK=64, 2-phase counted-vmcnt -----------
// v9: combines r4's fixes (3-bit XOR swizzle -> conflict-free reads; counted
// vmcnt(8), never 0 in-loop) with the m97-class occupancy gemm256 lost:
// LDS 64KB -> 2 blocks/CU; inter-block overlap hides the barrier drains.
// 256 thr = 4 waves (2M x 2N), per-wave 64x64 out (acc[4][4]).
// Epilogue: round-0's proven 256-thread LDS-staged coalesced epilogue.
// MODE 0 cls by n0>>10: 0=Q (scaled, O1), 1=K (O2), 2=V (transposed, O0).
// MODE 1: O0[M,N] fp32.
template<typename TO, int MODE>
__device__ __forceinline__ void epi128(
    f32x4 (&acc)[4][4], bf16* Ls, const float* __restrict__ bias,
    TO* __restrict__ O0, bf16* __restrict__ O1, bf16* __restrict__ O2,
    int N, int m0, int n0, int tid)
{
    const int lane = tid & 63;
    const int w = tid >> 6, wm = w >> 1, wn = w & 1;
    const int lr = lane & 15, quad = lane >> 4;
    const int cls = (MODE == 0) ? (n0 >> 10) : 1;

    if (MODE == 0 && cls == 2) {
        // V: stage transposed Cv[col][row], then coalesced stores along S
#pragma unroll
        for (int im = 0; im < 4; ++im) {
            int rowb = wm * 64 + im * 16 + quad * 4;
#pragma unroll
            for (int in = 0; in < 4; ++in) {
                int col = wn * 64 + in * 16 + lr;
                float bv = bias[n0 + col];
                bf16x4 pv;
#pragma unroll
                for (int r = 0; r < 4; ++r) pv[r] = (bf16)(acc[im][in][r] + bv);
                *(bf16x4*)&Ls[col * CPITCH + rowb] = pv;
            }
        }
        __syncthreads();
        const int b = m0 >> 11, s0 = m0 & 2047;
#pragma unroll
        for (int p = 0; p < 8; ++p) {
            int idx = tid + 256 * p;
            int col = idx & 127, mg = idx >> 7;
            bf16x8 v8 = *(const bf16x8*)&Ls[col * CPITCH + mg * 8];
            int ncol = n0 + col;
            int h = (ncol >> 6) & 15, hd = ncol & 63;
            *(bf16x8*)&((bf16*)O0)[((size_t)(b * NH + h) * NHD + hd) * NS + s0 + mg * 8] = v8;
        }
    } else {
#pragma unroll
        for (int im = 0; im < 4; ++im) {
            int rowb = wm * 64 + im * 16 + quad * 4;
#pragma unroll
            for (int in = 0; in < 4; ++in) {
                int col = wn * 64 + in * 16 + lr;
                float bv = bias[n0 + col];
#pragma unroll
                for (int r = 0; r < 4; ++r) {
                    float v = acc[im][in][r] + bv;
                    if (MODE == 0 && cls == 0) v *= QSCALE;
                    Ls[(rowb + r) * CPITCH + col] = (bf16)v;
                }
            }
        }
        __syncthreads();
#pragma unroll
        for (int p = 0; p < 8; ++p) {
            int idx = tid + 256 * p;
            int row = idx >> 4, colg = (idx & 15) * 8;
            bf16x8 v8 = *(const bf16x8*)&Ls[row * CPITCH + colg];
            if (MODE == 0) {
                int ncol = n0 + colg;
                int h = (ncol >> 6) & 15, hd = ncol & 63;
                int m = m0 + row, b = m >> 11, s = m & 2047;
                bf16* dst = (cls == 0) ? O1 : O2;
                *(bf16x8*)&dst[((size_t)(b * NH + h) * NS + s) * NHD + hd] = v8;
            } else {
                store8(&O0[(size_t)(m0 + row) * N + n0 + colg], v8);
            }
        }
    }
}

template<typename TO, int MODE>
__global__ __launch_bounds__(256, 2)
void gemm128(const bf16* __restrict__ Xp, const bf16* __restrict__ Wp,
             const float* __restrict__ bias, TO* __restrict__ O0,
             bf16* __restrict__ O1, bf16* __restrict__ O2, int N, int K)
{
    __shared__ __align__(16) bf16 L[32768];   // 64KB: dbuf d at d*16384 elems
    const int tid  = threadIdx.x;
    const int lane = tid & 63;
    const int w    = tid >> 6;
    const int lr   = lane & 15, quad = lane >> 4;
    const int wm   = w >> 1, wn = w & 1;
    const int m0   = blockIdx.y * 128;
    const int n0   = blockIdx.x * 128;

    // staging: per thread 4 A-chunks + 4 B-chunks (16B) per K-tile.
    // LDS dest linear (gload_lds); swizzled content via inverse-permuted
    // per-lane global source column: scol = ((lane&7) ^ (lane>>3)&7)*8.
    const int rb   = w * 32 + (lane >> 3);
    const int scol = ((lane & 7) ^ ((lane >> 3) & 7)) * 8;
    const bf16* gA = Xp + (size_t)(m0 + rb) * K + scol;
    const bf16* gB = Wp + (size_t)(n0 + rb) * K + scol;
    const int sdA  = w * 2048;            // + ip*512 ; wave-uniform, HW adds lane*16B
    const int sdB  = 8192 + w * 2048;

#define STAGE128(t) do { const int ko_ = (t) * 64;                              \
    bf16* Lb_ = &L[((t) & 1) * 16384];                                          \
    _Pragma("unroll")                                                           \
    for (int ip = 0; ip < 4; ++ip) {                                            \
        __builtin_amdgcn_global_load_lds((GU*)(gA + (size_t)ip * 8 * K + ko_),  \
                                         (LU*)&Lb_[sdA + ip * 512], 16, 0, 0);  \
        __builtin_amdgcn_global_load_lds((GU*)(gB + (size_t)ip * 8 * K + ko_),  \
                                         (LU*)&Lb_[sdB + ip * 512], 16, 0, 0);  \
    } } while (0)

    // fragment reads: row base + 3-bit XOR-swizzled column (incl. ks bit)
    const int cxor = (lr & 7) * 8;
    const int col0 = (0 * 32 + quad * 8) ^ cxor;
    const int col1 = (1 * 32 + quad * 8) ^ cxor;
    const int arow0 = (wm * 64 + lr) * 64;
    const int brow0 = 8192 + (wn * 64 + lr) * 64;

    f32x4 acc[4][4] = {};
    const int NT = K >> 6;

    STAGE128(0);
    STAGE128(1);
    WAIT_VM(8);          // tile 0's 8 loads done (tile 1's 8 in flight)
    BAR();

    for (int t = 0; t < NT; ++t) {
        const int db = (t & 1) * 16384;
        bf16x8 afr[2][4], bfr[2][4];
#pragma unroll
        for (int i = 0; i < 4; ++i) {
            afr[0][i] = *(const bf16x8*)&L[db + arow0 + i * 1024 + col0];
            afr[1][i] = *(const bf16x8*)&L[db + arow0 + i * 1024 + col1];
            bfr[0][i] = *(const bf16x8*)&L[db + brow0 + i * 1024 + col0];
            bfr[1][i] = *(const bf16x8*)&L[db + brow0 + i * 1024 + col1];
        }
        __builtin_amdgcn_s_setprio(1);
#pragma unroll
        for (int ks = 0; ks < 2; ++ks)
#pragma unroll
            for (int im = 0; im < 4; ++im)
#pragma unroll
                for (int in = 0; in < 4; ++in)
                    acc[im][in] = __builtin_amdgcn_mfma_f32_16x16x32_bf16(
                        afr[ks][im], bfr[ks][in], acc[im][in], 0, 0, 0);
        __builtin_amdgcn_s_setprio(0);
        BAR();                       // all waves done reading buf[t&1]
        if (t + 2 < NT) { STAGE128(t + 2); WAIT_VM(8); }   // t+1 done, t+2 in flight
        else WAIT_VM(0);                                    // tail drain
        BAR();                       // buf[(t+1)&1] ready for next iteration
    }
#undef STAGE128

    epi128<TO, MODE>(acc, L, bias, O0, O1, O2, N, m0, n0, tid);
}

// Flash attention, causal, fixed-shift log2 softmax, P kept in REGISTERS.
// v5 (round-8 proven): 128 q-rows/block, 2 q-groups/wave, T14 reg-prefetch,
// K/V LDS double-buffer (1 barrier/tile), T5 setprio around MFMA clusters.
__global__ __launch_bounds__(256, 3)
void attn_kernel(const bf16* __restrict__ Q, const bf16* __restrict__ K,
                 const bf16* __restrict__ Vt_g, bf16* __restrict__ ctx)
{
    const int jt = 15 - (blockIdx.x >> 6);   // Q-tile index (128 rows), heavy first
    const int bh = blockIdx.x & 63;
    const int b  = bh >> 4, h = bh & 15;
    const int q0 = jt * 128;
    const bf16* Qp = Q + (size_t)bh * NS * NHD;
    const bf16* Kp = K + (size_t)bh * NS * NHD;
    const bf16* Vp = Vt_g + (size_t)bh * NHD * NS;   // [hd][S]

    __shared__ union {
        struct { bf16 Kh[64 * 72]; bf16 Vh[64 * 72]; } s[2];
        bf16 QO[128 * 72];
    } u;

    const int tid  = threadIdx.x;
    const int lane = tid & 63;
    const int w    = tid >> 6;
    const int lr   = lane & 15, quad = lane >> 4;

    const int srow = tid >> 3;
    const int sch  = (tid & 7) * 8;

    // T14 prefetch registers: K/V tile in flight during compute
    bf16x8 kreg[2], vreg[2];
#pragma unroll
    for (int i = 0; i < 2; ++i) {
        kreg[i] = *(const bf16x8*)(Kp + (size_t)(srow + 32 * i) * NHD + sch);
        vreg[i] = *(const bf16x8*)(Vp + (size_t)(srow + 32 * i) * NS + sch);
    }

    // stage Q while the kt=0 K/V loads are in flight
#pragma unroll
    for (int i = 0; i < 4; ++i) {
        int row = srow + 32 * i;
        *(bf16x8*)(&u.QO[sw(row, sch)]) =
            *(const bf16x8*)(Qp + (size_t)(q0 + row) * NHD + sch);
    }
    __syncthreads();

    // hoist Q-fragments (k-loop invariant): qf[qg][ks]
    bf16x8 qf[2][2];
#pragma unroll
    for (int qg = 0; qg < 2; ++qg)
#pragma unroll
        for (int ks = 0; ks < 2; ++ks)
            qf[qg][ks] = *(const bf16x8*)(&u.QO[sw(w * 32 + qg * 16 + lr, ks * 32 + quad * 8)]);
    __syncthreads();   // QO region dead; Kh/Vh writes may begin

    float l_part[2] = {0.f, 0.f};
    f32x4 acco[2][4] = {};           // O^T per qg: hd = jn*16+quad*4+r, col = q

    const int wq0 = q0 + w * 32;     // this wave's first q row
    const int nkt = 2 * jt + 2;
    for (int kt = 0; kt < nkt; ++kt) {
        bf16* Kh = u.s[kt & 1].Kh;
        bf16* Vh = u.s[kt & 1].Vh;
        // reg -> LDS buf[kt&1] (vmcnt waited via register dep)
#pragma unroll
        for (int i = 0; i < 2; ++i) {
            *(bf16x8*)(&Kh[sw(srow + 32 * i, sch)]) = kreg[i];
            *(bf16x8*)(&Vh[sw(srow + 32 * i, sch)]) = vreg[i];
        }
        // issue next tile's global loads; land during compute below
        if (kt + 1 < nkt) {
#pragma unroll
            for (int i = 0; i < 2; ++i) {
                kreg[i] = *(const bf16x8*)(Kp + (size_t)((kt + 1) * 64 + srow + 32 * i) * NHD + sch);
                vreg[i] = *(const bf16x8*)(Vp + (size_t)(srow + 32 * i) * NS + (kt + 1) * 64 + sch);
            }
        }
        __syncthreads();   // buf[kt&1] ready; ONLY barrier in the tile

        if (kt * 64 <= wq0 + 31) {
            // S^T = K @ Q^T: one K-frag read feeds BOTH q-groups
            f32x4 sacc[2][4] = {};
#pragma unroll
            for (int ks = 0; ks < 2; ++ks) {
#pragma unroll
                for (int kn = 0; kn < 4; ++kn) {
                    bf16x8 ak = *(const bf16x8*)(&Kh[sw(kn * 16 + lr, ks * 32 + quad * 8)]);
                    __builtin_amdgcn_s_setprio(1);
                    sacc[0][kn] = __builtin_amdgcn_mfma_f32_16x16x32_bf16(ak, qf[0][ks], sacc[0][kn], 0, 0, 0);
                    sacc[1][kn] = __builtin_amdgcn_mfma_f32_16x16x32_bf16(ak, qf[1][ks], sacc[1][kn], 0, 0, 0);
                    __builtin_amdgcn_s_setprio(0);
                }
            }

            // softmax in registers; p-values land directly in x16 B-frag layout
            const bool diag = (kt * 64 + 63 > wq0);
            bf16x4 pf[2][4];
#pragma unroll
            for (int qg = 0; qg < 2; ++qg) {
                const int qrow = wq0 + qg * 16 + lr;
#pragma unroll
                for (int kn = 0; kn < 4; ++kn) {
#pragma unroll
                    for (int r = 0; r < 4; ++r) {
                        float x = sacc[qg][kn][r];
                        if (diag) {
                            int kcol = kt * 64 + kn * 16 + quad * 4 + r;
                            x = (kcol <= qrow) ? x : -INFINITY;
                        }
                        float p = __builtin_amdgcn_exp2f(x - FMAX);  // -inf -> 0
                        l_part[qg] += p;
                        pf[qg][kn][r] = (bf16)p;
                    }
                }
            }

            // O^T += V^T @ P^T: one V-frag read feeds BOTH q-groups
#pragma unroll
            for (int kn = 0; kn < 4; ++kn) {
#pragma unroll
                for (int jn = 0; jn < 4; ++jn) {
                    bf16x4 av = *(const bf16x4*)(&Vh[sw(jn * 16 + lr, kn * 16 + quad * 4)]);
                    __builtin_amdgcn_s_setprio(1);
                    acco[0][jn] = mfma16(av, pf[0][kn], acco[0][jn]);
                    acco[1][jn] = mfma16(av, pf[1][kn], acco[1][jn]);
                    __builtin_amdgcn_s_setprio(0);
                }
            }
        }
        // no trailing barrier: next write targets buf[(kt+1)&1], last read at
        // kt-1 and fenced by THIS tile's barrier on the following iteration
    }

    // l lives per-lane (one qrow per lane per qg); reduce across the 4 quads
    float rinv[2];
#pragma unroll
    for (int qg = 0; qg < 2; ++qg) {
        float l = l_part[qg];
        l += __shfl_xor(l, 16);
        l += __shfl_xor(l, 32);
        rinv[qg] = 1.0f / l;
    }

    // epilogue: O^T -> QO (dead) as packed b64 rows, then coalesced b128 out
    __syncthreads();
#pragma unroll
    for (int qg = 0; qg < 2; ++qg)
#pragma unroll
        for (int jn = 0; jn < 4; ++jn) {
            bf16x4 pv;
#pragma unroll
            for (int r = 0; r < 4; ++r) pv[r] = (bf16)(acco[qg][jn][r] * rinv[qg]);
            *(bf16x4*)&u.QO[(w * 32 + qg * 16 + lr) * 72 + jn * 16 + quad * 4] = pv;
        }
    __syncthreads();
#pragma unroll
    for (int p = 0; p < 4; ++p) {
        int idx = tid + 256 * p;
        int row = idx >> 3, colg = (idx & 7) * 8;
        bf16x8 v8 = *(const bf16x8*)&u.QO[row * 72 + colg];
        *(bf16x8*)&ctx[((size_t)(b * NS) + q0 + row) * ND + h * NHD + colg] = v8;
    }
}

extern "C" void kernel_launch(void* const* d_in, const int* in_sizes, int n_in,
                              void* d_out, int out_size, void* d_ws, size_t ws_size,
                              hipStream_t stream) {
    const float* x     = (const float*)d_in[0];
    const float* Wqkv  = (const float*)d_in[1];
    const float* bqkv  = (const float*)d_in[2];
    const float* Wproj = (const float*)d_in[3];
    const float* bproj = (const float*)d_in[4];
    float* out = (float*)d_out;

    const size_t per = (size_t)NB * NH * NS * NHD;  // 8,388,608 elems
    bf16* q_ws = (bf16*)d_ws;
    bf16* k_ws = q_ws + per;
    bf16* v_ws = k_ws + per;        // V transposed [B,H,HD,S]
    bf16* x_bf = v_ws + per;        // x as bf16; reused as ctx after QKV GEMM
    bf16* c_ws = x_bf;              // alias: x_bf dead once QKV GEMM completes
    bf16* wq_bf = x_bf + per;       // Wqkv bf16
    bf16* wp_bf = wq_bf + (size_t)3 * ND * ND;  // Wproj bf16

    const int n0 = NB * NS * ND;        // 8,388,608
    const int n1 = 3 * ND * ND;         // 3,145,728
    const int n2 = ND * ND;             // 1,048,576
    convert_kernel<<<(n0 + n1 + n2) / (256 * 8), 256, 0, stream>>>(
        x, x_bf, n0, Wqkv, wq_bf, n1, Wproj, wp_bf, n2);

    // QKV: 128x128 tiles -> grid 24x64 = 1536 blocks = 6/CU at 2 blocks/CU
    dim3 gq(3 * ND / 128, NB * NS / 128);
    gemm128<bf16, 0><<<gq, 256, 0, stream>>>(
        x_bf, wq_bf, bqkv, v_ws, q_ws, k_ws, 3 * ND, ND);

    // attn: 128 q-rows/block -> 16 jt x 64 bh = 1024 blocks
    attn_kernel<<<dim3(NB * NH * 16), 256, 0, stream>>>(q_ws, k_ws, v_ws, c_ws);

    // proj: 128x128 tiles -> grid 8x64 = 512 blocks = exactly 2/CU
    dim3 gp(ND / 128, NB * NS / 128);
    gemm128<float, 1><<<gp, 256, 0, stream>>>(
        c_ws, wp_bf, bproj, out, nullptr, nullptr, ND, ND);
}

// Round 10
// 244.395 us; speedup vs baseline: 1.0866x; 1.0866x over previous
//
#include <hip/hip_runtime.h>
#include <stdint.h>

typedef __bf16 bf16;
typedef __bf16 bf16x4 __attribute__((ext_vector_type(4)));
typedef __bf16 bf16x8 __attribute__((ext_vector_type(8)));
typedef float f32x4 __attribute__((ext_vector_type(4)));
typedef short short4v __attribute__((ext_vector_type(4)));

#define NB 4
#define NS 2048
#define ND 1024
#define NH 16
#define NHD 64
#define QSCALE 0.1803368801111204f   // 0.125 * log2(e): scores in log2 domain
#define FMAX   8.0f                  // fixed softmax shift (log2 domain)
#define CPITCH 136                   // epilogue LDS pitch: 272B rows, 16B aligned

typedef const __attribute__((address_space(1))) unsigned GU;
typedef __attribute__((address_space(3))) unsigned LU;

#define WAIT_VM(n) asm volatile("s_waitcnt vmcnt(" #n ")" ::: "memory")
#define BAR() do { asm volatile("" ::: "memory"); __builtin_amdgcn_s_barrier(); \
                   asm volatile("" ::: "memory"); } while (0)

__device__ __forceinline__ bf16x8 load8f(const float* p) {
    float4 a = *(const float4*)p;
    float4 b = *(const float4*)(p + 4);
    bf16x8 r;
    r[0] = (bf16)a.x; r[1] = (bf16)a.y; r[2] = (bf16)a.z; r[3] = (bf16)a.w;
    r[4] = (bf16)b.x; r[5] = (bf16)b.y; r[6] = (bf16)b.z; r[7] = (bf16)b.w;
    return r;
}
__device__ __forceinline__ void store8(bf16* p, bf16x8 v) { *(bf16x8*)p = v; }
__device__ __forceinline__ void store8(float* p, bf16x8 v) {
    float4 a; a.x = (float)v[0]; a.y = (float)v[1]; a.z = (float)v[2]; a.w = (float)v[3];
    float4 b; b.x = (float)v[4]; b.y = (float)v[5]; b.z = (float)v[6]; b.w = (float)v[7];
    *(float4*)p = a; *(float4*)(p + 4) = b;
}

// 16x16x16 bf16 MFMA (K=16): A/B frags are 4 bf16/lane, k = quad*4+j.
__device__ __forceinline__ f32x4 mfma16(bf16x4 a, bf16x4 b, f32x4 c) {
#ifdef __HIP_DEVICE_COMPILE__
#if __has_builtin(__builtin_amdgcn_mfma_f32_16x16x16bf16_1k)
    return __builtin_amdgcn_mfma_f32_16x16x16bf16_1k(
        __builtin_bit_cast(short4v, a), __builtin_bit_cast(short4v, b), c, 0, 0, 0);
#else
    f32x4 d;
    asm("v_mfma_f32_16x16x16_bf16 %0, %1, %2, %3"
        : "=v"(d) : "v"(a), "v"(b), "v"(c));
    return d;
#endif
#else
    return c;  // host stub, never executed
#endif
}

// attn LDS swizzle: XOR col by quad-of-row*16; preserves >=4-elem contiguity.
__device__ __forceinline__ int sw(int row, int col) {
    return row * 72 + (col ^ (((row >> 2) & 3) * 16));
}

// T1 bijective XCD swizzle (m204): each XCD gets a contiguous chunk of the
// linear grid -> neighbor tiles (sharing A-panels) land on the same L2.
// Requires nothing of nwg; simple path when nwg%8==0 (all our grids).
__device__ __forceinline__ int xcd_swz(int orig, int nwg) {
    int q = nwg >> 3, r = nwg & 7;
    int xcd = orig & 7, pos = orig >> 3;
    return (xcd < r ? xcd * (q + 1) : r * (q + 1) + (xcd - r) * q) + pos;
}

// One-shot fp32 -> bf16 conversion of x, Wqkv, Wproj (biases stay fp32).
__global__ __launch_bounds__(256)
void convert_kernel(const float* __restrict__ s0, bf16* __restrict__ d0, int n0,
                    const float* __restrict__ s1, bf16* __restrict__ d1, int n1,
                    const float* __restrict__ s2, bf16* __restrict__ d2, int n2)
{
    int idx = (blockIdx.x * 256 + threadIdx.x) * 8;
    const float* s; bf16* d;
    if (idx < n0)              { s = s0 + idx;  d = d0 + idx; }
    else if ((idx -= n0) < n1) { s = s1 + idx;  d = d1 + idx; }
    else if ((idx -= n1) < n2) { s = s2 + idx;  d = d2 + idx; }
    else return;
    *(bf16x8*)d = load8f(s);
}

// ---------------- 128x128-tile GEMM, BK=64, 2-phase counted-vmcnt -----------
// v9 structure (proven round 9: QKV <= 70.8us) + v10: T1 XCD swizzle.
// 256 thr = 4 waves (2M x 2N), per-wave 64x64 out; LDS 64KB -> 2 blocks/CU;
// 3-bit XOR swizzle (conflict-free reads, ~2e5); counted vmcnt(8), never 0.
template<typename TO, int MODE>
__device__ __forceinline__ void epi128(
    f32x4 (&acc)[4][4], bf16* Ls, const float* __restrict__ bias,
    TO* __restrict__ O0, bf16* __restrict__ O1, bf16* __restrict__ O2,
    int N, int m0, int n0, int tid)
{
    const int lane = tid & 63;
    const int w = tid >> 6, wm = w >> 1, wn = w & 1;
    const int lr = lane & 15, quad = lane >> 4;
    const int cls = (MODE == 0) ? (n0 >> 10) : 1;

    if (MODE == 0 && cls == 2) {
        // V: stage transposed Cv[col][row], then coalesced stores along S
#pragma unroll
        for (int im = 0; im < 4; ++im) {
            int rowb = wm * 64 + im * 16 + quad * 4;
#pragma unroll
            for (int in = 0; in < 4; ++in) {
                int col = wn * 64 + in * 16 + lr;
                float bv = bias[n0 + col];
                bf16x4 pv;
#pragma unroll
                for (int r = 0; r < 4; ++r) pv[r] = (bf16)(acc[im][in][r] + bv);
                *(bf16x4*)&Ls[col * CPITCH + rowb] = pv;
            }
        }
        __syncthreads();
        const int b = m0 >> 11, s0 = m0 & 2047;
#pragma unroll
        for (int p = 0; p < 8; ++p) {
            int idx = tid + 256 * p;
            int col = idx & 127, mg = idx >> 7;
            bf16x8 v8 = *(const bf16x8*)&Ls[col * CPITCH + mg * 8];
            int ncol = n0 + col;
            int h = (ncol >> 6) & 15, hd = ncol & 63;
            *(bf16x8*)&((bf16*)O0)[((size_t)(b * NH + h) * NHD + hd) * NS + s0 + mg * 8] = v8;
        }
    } else {
#pragma unroll
        for (int im = 0; im < 4; ++im) {
            int rowb = wm * 64 + im * 16 + quad * 4;
#pragma unroll
            for (int in = 0; in < 4; ++in) {
                int col = wn * 64 + in * 16 + lr;
                float bv = bias[n0 + col];
#pragma unroll
                for (int r = 0; r < 4; ++r) {
                    float v = acc[im][in][r] + bv;
                    if (MODE == 0 && cls == 0) v *= QSCALE;
                    Ls[(rowb + r) * CPITCH + col] = (bf16)v;
                }
            }
        }
        __syncthreads();
#pragma unroll
        for (int p = 0; p < 8; ++p) {
            int idx = tid + 256 * p;
            int row = idx >> 4, colg = (idx & 15) * 8;
            bf16x8 v8 = *(const bf16x8*)&Ls[row * CPITCH + colg];
            if (MODE == 0) {
                int ncol = n0 + colg;
                int h = (ncol >> 6) & 15, hd = ncol & 63;
                int m = m0 + row, b = m >> 11, s = m & 2047;
                bf16* dst = (cls == 0) ? O1 : O2;
                *(bf16x8*)&dst[((size_t)(b * NH + h) * NS + s) * NHD + hd] = v8;
            } else {
                store8(&O0[(size_t)(m0 + row) * N + n0 + colg], v8);
            }
        }
    }
}

template<typename TO, int MODE>
__global__ __launch_bounds__(256, 2)
void gemm128(const bf16* __restrict__ Xp, const bf16* __restrict__ Wp,
             const float* __restrict__ bias, TO* __restrict__ O0,
             bf16* __restrict__ O1, bf16* __restrict__ O2, int N, int K)
{
    __shared__ __align__(16) bf16 L[32768];   // 64KB: dbuf d at d*16384 elems
    const int tid  = threadIdx.x;
    const int lane = tid & 63;
    const int w    = tid >> 6;
    const int lr   = lane & 15, quad = lane >> 4;
    const int wm   = w >> 1, wn = w & 1;

    // T1: remap dispatch slot -> tile so each XCD gets contiguous y-rows
    const int gx   = gridDim.x;
    const int nwg  = gx * gridDim.y;
    const int swz  = xcd_swz(blockIdx.y * gx + blockIdx.x, nwg);
    const int m0   = (swz / gx) * 128;
    const int n0   = (swz % gx) * 128;

    // staging: per thread 4 A-chunks + 4 B-chunks (16B) per K-tile.
    // LDS dest linear (gload_lds); swizzled content via inverse-permuted
    // per-lane global source column: scol = ((lane&7) ^ (lane>>3)&7)*8.
    const int rb   = w * 32 + (lane >> 3);
    const int scol = ((lane & 7) ^ ((lane >> 3) & 7)) * 8;
    const bf16* gA = Xp + (size_t)(m0 + rb) * K + scol;
    const bf16* gB = Wp + (size_t)(n0 + rb) * K + scol;
    const int sdA  = w * 2048;            // + ip*512 ; wave-uniform, HW adds lane*16B
    const int sdB  = 8192 + w * 2048;

#define STAGE128(t) do { const int ko_ = (t) * 64;                              \
    bf16* Lb_ = &L[((t) & 1) * 16384];                                          \
    _Pragma("unroll")                                                           \
    for (int ip = 0; ip < 4; ++ip) {                                            \
        __builtin_amdgcn_global_load_lds((GU*)(gA + (size_t)ip * 8 * K + ko_),  \
                                         (LU*)&Lb_[sdA + ip * 512], 16, 0, 0);  \
        __builtin_amdgcn_global_load_lds((GU*)(gB + (size_t)ip * 8 * K + ko_),  \
                                         (LU*)&Lb_[sdB + ip * 512], 16, 0, 0);  \
    } } while (0)

    // fragment reads: row base + 3-bit XOR-swizzled column (incl. ks bit)
    const int cxor = (lr & 7) * 8;
    const int col0 = (0 * 32 + quad * 8) ^ cxor;
    const int col1 = (1 * 32 + quad * 8) ^ cxor;
    const int arow0 = (wm * 64 + lr) * 64;
    const int brow0 = 8192 + (wn * 64 + lr) * 64;

    f32x4 acc[4][4] = {};
    const int NT = K >> 6;

    STAGE128(0);
    STAGE128(1);
    WAIT_VM(8);          // tile 0's 8 loads done (tile 1's 8 in flight)
    BAR();

    for (int t = 0; t < NT; ++t) {
        const int db = (t & 1) * 16384;
        bf16x8 afr[2][4], bfr[2][4];
#pragma unroll
        for (int i = 0; i < 4; ++i) {
            afr[0][i] = *(const bf16x8*)&L[db + arow0 + i * 1024 + col0];
            afr[1][i] = *(const bf16x8*)&L[db + arow0 + i * 1024 + col1];
            bfr[0][i] = *(const bf16x8*)&L[db + brow0 + i * 1024 + col0];
            bfr[1][i] = *(const bf16x8*)&L[db + brow0 + i * 1024 + col1];
        }
        __builtin_amdgcn_s_setprio(1);
#pragma unroll
        for (int ks = 0; ks < 2; ++ks)
#pragma unroll
            for (int im = 0; im < 4; ++im)
#pragma unroll
                for (int in = 0; in < 4; ++in)
                    acc[im][in] = __builtin_amdgcn_mfma_f32_16x16x32_bf16(
                        afr[ks][im], bfr[ks][in], acc[im][in], 0, 0, 0);
        __builtin_amdgcn_s_setprio(0);
        BAR();                       // all waves done reading buf[t&1]
        if (t + 2 < NT) { STAGE128(t + 2); WAIT_VM(8); }   // t+1 done, t+2 in flight
        else WAIT_VM(0);                                    // tail drain
        BAR();                       // buf[(t+1)&1] ready for next iteration
    }
#undef STAGE128

    epi128<TO, MODE>(acc, L, bias, O0, O1, O2, N, m0, n0, tid);
}

// Flash attention, causal, fixed-shift log2 softmax, P kept in REGISTERS.
// v6 = v5 (r8-proven: dbuf K/V, 1 barrier/tile, T14 reg-prefetch) +
//  (a) l via ones-MFMA: acc_l = mfma16(ones, pf) sums p on the MFMA pipe,
//      deleting 32 VALU adds/tile + the cross-quad shuffle (VALU was 52%,
//      the co-critical pipe; MFMA at 31% has headroom);
//  (b) setprio hoisted to cluster level (was toggled 24x/tile).
__global__ __launch_bounds__(256, 3)
void attn_kernel(const bf16* __restrict__ Q, const bf16* __restrict__ K,
                 const bf16* __restrict__ Vt_g, bf16* __restrict__ ctx)
{
    const int jt = 15 - (blockIdx.x >> 6);   // Q-tile index (128 rows), heavy first
    const int bh = blockIdx.x & 63;
    const int b  = bh >> 4, h = bh & 15;
    const int q0 = jt * 128;
    const bf16* Qp = Q + (size_t)bh * NS * NHD;
    const bf16* Kp = K + (size_t)bh * NS * NHD;
    const bf16* Vp = Vt_g + (size_t)bh * NHD * NS;   // [hd][S]

    __shared__ union {
        struct { bf16 Kh[64 * 72]; bf16 Vh[64 * 72]; } s[2];
        bf16 QO[128 * 72];
    } u;

    const int tid  = threadIdx.x;
    const int lane = tid & 63;
    const int w    = tid >> 6;
    const int lr   = lane & 15, quad = lane >> 4;

    const int srow = tid >> 3;
    const int sch  = (tid & 7) * 8;

    // T14 prefetch registers: K/V tile in flight during compute
    bf16x8 kreg[2], vreg[2];
#pragma unroll
    for (int i = 0; i < 2; ++i) {
        kreg[i] = *(const bf16x8*)(Kp + (size_t)(srow + 32 * i) * NHD + sch);
        vreg[i] = *(const bf16x8*)(Vp + (size_t)(srow + 32 * i) * NS + sch);
    }

    // stage Q while the kt=0 K/V loads are in flight
#pragma unroll
    for (int i = 0; i < 4; ++i) {
        int row = srow + 32 * i;
        *(bf16x8*)(&u.QO[sw(row, sch)]) =
            *(const bf16x8*)(Qp + (size_t)(q0 + row) * NHD + sch);
    }
    __syncthreads();

    // hoist Q-fragments (k-loop invariant): qf[qg][ks]
    bf16x8 qf[2][2];
#pragma unroll
    for (int qg = 0; qg < 2; ++qg)
#pragma unroll
        for (int ks = 0; ks < 2; ++ks)
            qf[qg][ks] = *(const bf16x8*)(&u.QO[sw(w * 32 + qg * 16 + lr, ks * 32 + quad * 8)]);
    __syncthreads();   // QO region dead; Kh/Vh writes may begin

    const bf16 one = (bf16)1.0f;
    const bf16x4 ones4 = {one, one, one, one};
    f32x4 accl[2] = {};              // l per qg via ones-MFMA (all rows equal)
    f32x4 acco[2][4] = {};           // O^T per qg: hd = jn*16+quad*4+r, col = q

    const int wq0 = q0 + w * 32;     // this wave's first q row
    const int nkt = 2 * jt + 2;
    for (int kt = 0; kt < nkt; ++kt) {
        bf16* Kh = u.s[kt & 1].Kh;
        bf16* Vh = u.s[kt & 1].Vh;
        // reg -> LDS buf[kt&1] (vmcnt waited via register dep)
#pragma unroll
        for (int i = 0; i < 2; ++i) {
            *(bf16x8*)(&Kh[sw(srow + 32 * i, sch)]) = kreg[i];
            *(bf16x8*)(&Vh[sw(srow + 32 * i, sch)]) = vreg[i];
        }
        // issue next tile's global loads; land during compute below
        if (kt + 1 < nkt) {
#pragma unroll
            for (int i = 0; i < 2; ++i) {
                kreg[i] = *(const bf16x8*)(Kp + (size_t)((kt + 1) * 64 + srow + 32 * i) * NHD + sch);
                vreg[i] = *(const bf16x8*)(Vp + (size_t)(srow + 32 * i) * NS + (kt + 1) * 64 + sch);
            }
        }
        __syncthreads();   // buf[kt&1] ready; ONLY barrier in the tile

        if (kt * 64 <= wq0 + 31) {
            // S^T = K @ Q^T: one K-frag read feeds BOTH q-groups
            f32x4 sacc[2][4] = {};
            __builtin_amdgcn_s_setprio(1);
#pragma unroll
            for (int ks = 0; ks < 2; ++ks) {
#pragma unroll
                for (int kn = 0; kn < 4; ++kn) {
                    bf16x8 ak = *(const bf16x8*)(&Kh[sw(kn * 16 + lr, ks * 32 + quad * 8)]);
                    sacc[0][kn] = __builtin_amdgcn_mfma_f32_16x16x32_bf16(ak, qf[0][ks], sacc[0][kn], 0, 0, 0);
                    sacc[1][kn] = __builtin_amdgcn_mfma_f32_16x16x32_bf16(ak, qf[1][ks], sacc[1][kn], 0, 0, 0);
                }
            }
            __builtin_amdgcn_s_setprio(0);

            // softmax in registers; p-values land directly in x16 B-frag layout
            const bool diag = (kt * 64 + 63 > wq0);
            bf16x4 pf[2][4];
#pragma unroll
            for (int qg = 0; qg < 2; ++qg) {
                const int qrow = wq0 + qg * 16 + lr;
#pragma unroll
                for (int kn = 0; kn < 4; ++kn) {
#pragma unroll
                    for (int r = 0; r < 4; ++r) {
                        float x = sacc[qg][kn][r];
                        if (diag) {
                            int kcol = kt * 64 + kn * 16 + quad * 4 + r;
                            x = (kcol <= qrow) ? x : -INFINITY;
                        }
                        float p = __builtin_amdgcn_exp2f(x - FMAX);  // -inf -> 0
                        pf[qg][kn][r] = (bf16)p;
                    }
                }
            }

            // O^T += V^T @ P^T (+ l += 1 @ P^T on the MFMA pipe)
            __builtin_amdgcn_s_setprio(1);
#pragma unroll
            for (int kn = 0; kn < 4; ++kn) {
#pragma unroll
                for (int jn = 0; jn < 4; ++jn) {
                    bf16x4 av = *(const bf16x4*)(&Vh[sw(jn * 16 + lr, kn * 16 + quad * 4)]);
                    acco[0][jn] = mfma16(av, pf[0][kn], acco[0][jn]);
                    acco[1][jn] = mfma16(av, pf[1][kn], acco[1][jn]);
                }
                accl[0] = mfma16(ones4, pf[0][kn], accl[0]);
                accl[1] = mfma16(ones4, pf[1][kn], accl[1]);
            }
            __builtin_amdgcn_s_setprio(0);
        }
        // no trailing barrier: next write targets buf[(kt+1)&1], last read at
        // kt-1 and fenced by THIS tile's barrier on the following iteration
    }

    // l = accl[qg][any r] (every output row of ones@P^T equals the col-sum)
    float rinv[2];
#pragma unroll
    for (int qg = 0; qg < 2; ++qg) rinv[qg] = 1.0f / accl[qg][0];

    // epilogue: O^T -> QO (dead) as packed b64 rows, then coalesced b128 out
    __syncthreads();
#pragma unroll
    for (int qg = 0; qg < 2; ++qg)
#pragma unroll
        for (int jn = 0; jn < 4; ++jn) {
            bf16x4 pv;
#pragma unroll
            for (int r = 0; r < 4; ++r) pv[r] = (bf16)(acco[qg][jn][r] * rinv[qg]);
            *(bf16x4*)&u.QO[(w * 32 + qg * 16 + lr) * 72 + jn * 16 + quad * 4] = pv;
        }
    __syncthreads();
#pragma unroll
    for (int p = 0; p < 4; ++p) {
        int idx = tid + 256 * p;
        int row = idx >> 3, colg = (idx & 7) * 8;
        bf16x8 v8 = *(const bf16x8*)&u.QO[row * 72 + colg];
        *(bf16x8*)&ctx[((size_t)(b * NS) + q0 + row) * ND + h * NHD + colg] = v8;
    }
}

extern "C" void kernel_launch(void* const* d_in, const int* in_sizes, int n_in,
                              void* d_out, int out_size, void* d_ws, size_t ws_size,
                              hipStream_t stream) {
    const float* x     = (const float*)d_in[0];
    const float* Wqkv  = (const float*)d_in[1];
    const float* bqkv  = (const float*)d_in[2];
    const float* Wproj = (const float*)d_in[3];
    const float* bproj = (const float*)d_in[4];
    float* out = (float*)d_out;

    const size_t per = (size_t)NB * NH * NS * NHD;  // 8,388,608 elems
    bf16* q_ws = (bf16*)d_ws;
    bf16* k_ws = q_ws + per;
    bf16* v_ws = k_ws + per;        // V transposed [B,H,HD,S]
    bf16* x_bf = v_ws + per;        // x as bf16; reused as ctx after QKV GEMM
    bf16* c_ws = x_bf;              // alias: x_bf dead once QKV GEMM completes
    bf16* wq_bf = x_bf + per;       // Wqkv bf16
    bf16* wp_bf = wq_bf + (size_t)3 * ND * ND;  // Wproj bf16

    const int n0 = NB * NS * ND;        // 8,388,608
    const int n1 = 3 * ND * ND;         // 3,145,728
    const int n2 = ND * ND;             // 1,048,576
    convert_kernel<<<(n0 + n1 + n2) / (256 * 8), 256, 0, stream>>>(
        x, x_bf, n0, Wqkv, wq_bf, n1, Wproj, wp_bf, n2);

    // QKV: 128x128 tiles -> grid 24x64 = 1536 blocks (T1-swizzled)
    dim3 gq(3 * ND / 128, NB * NS / 128);
    gemm128<bf16, 0><<<gq, 256, 0, stream>>>(
        x_bf, wq_bf, bqkv, v_ws, q_ws, k_ws, 3 * ND, ND);

    // attn: 128 q-rows/block -> 16 jt x 64 bh = 1024 blocks
    attn_kernel<<<dim3(NB * NH * 16), 256, 0, stream>>>(q_ws, k_ws, v_ws, c_ws);

    // proj: 128x128 tiles -> grid 8x64 = 512 blocks (T1-swizzled)
    dim3 gp(ND / 128, NB * NS / 128);
    gemm128<float, 1><<<gp, 256, 0, stream>>>(
        c_ws, wp_bf, bproj, out, nullptr, nullptr, ND, ND);
}